// Round 4
// baseline (1731.501 us; speedup 1.0000x reference)
//
#include <hip/hip_runtime.h>
#include <math.h>

// Problem constants (B,T,E)=(4,2048,2048), NH=16, NKV=4, HD=128
constexpr int Bc   = 4;
constexpr int Tc   = 2048;
constexpr int Ec   = 2048;
constexpr int NHc  = 16;
constexpr int NKVc = 4;
constexpr int HDc  = 128;
constexpr int KVEc = NKVc * HDc; // 512

typedef __attribute__((ext_vector_type(8))) short bf16x8;
typedef __attribute__((ext_vector_type(4))) short short4v;
typedef __attribute__((ext_vector_type(4))) float f32x4;

__device__ __forceinline__ short f2bf(float f) {   // round-to-nearest-even
    union { float f; unsigned u; } v; v.f = f;
    unsigned r = v.u + 0x7FFF + ((v.u >> 16) & 1);
    return (short)(r >> 16);
}
__device__ __forceinline__ float bf2f(short s) {
    union { unsigned u; float f; } v; v.u = ((unsigned)(unsigned short)s) << 16;
    return v.f;
}
// async global->LDS, 16B per lane; LDS dest = wave-uniform base + lane*16
__device__ __forceinline__ void gload16(const void* g, void* l) {
    __builtin_amdgcn_global_load_lds(
        (const __attribute__((address_space(1))) unsigned*)g,
        (__attribute__((address_space(3))) unsigned*)l, 16, 0, 0);
}

// ---------------------------------------------------------------------------
// Prep: x fp32 -> hi/lo bf16 (same layout)
// ---------------------------------------------------------------------------
__global__ __launch_bounds__(256)
void convert_split(const float* __restrict__ X, short* __restrict__ Xhi,
                   short* __restrict__ Xlo)
{
    int i = blockIdx.x * 256 + threadIdx.x;    // float4 index
    float4 v = ((const float4*)X)[i];
    float fv[4] = {v.x, v.y, v.z, v.w};
    short4v hi, lo;
    #pragma unroll
    for (int j = 0; j < 4; ++j) {
        hi[j] = f2bf(fv[j]);
        lo[j] = f2bf(fv[j] - bf2f(hi[j]));
    }
    ((short4v*)Xhi)[i] = hi;
    ((short4v*)Xlo)[i] = lo;
}

// ---------------------------------------------------------------------------
// Prep: W [K][N] fp32 -> WT hi (and optional lo) [N][K] bf16
// ---------------------------------------------------------------------------
__global__ __launch_bounds__(256)
void transpose_split(const float* __restrict__ W, short* __restrict__ WThi,
                     short* __restrict__ WTlo, int K, int N)
{
    __shared__ float Ls[32][33];
    const int k0 = blockIdx.x * 32, n0 = blockIdx.y * 32;
    const int t = threadIdx.x;
    const int r = t >> 3, c4 = (t & 7) << 2;
    float4 v = *(const float4*)(W + (size_t)(k0 + r) * N + n0 + c4);
    Ls[r][c4 + 0] = v.x; Ls[r][c4 + 1] = v.y;
    Ls[r][c4 + 2] = v.z; Ls[r][c4 + 3] = v.w;
    __syncthreads();
    short4v hi, lo;
    #pragma unroll
    for (int i = 0; i < 4; ++i) {
        float f = Ls[c4 + i][r];
        hi[i] = f2bf(f);
        lo[i] = f2bf(f - bf2f(hi[i]));
    }
    *(short4v*)(WThi + (size_t)(n0 + r) * K + k0 + c4) = hi;
    if (WTlo) *(short4v*)(WTlo + (size_t)(n0 + r) * K + k0 + c4) = lo;
}

// ---------------------------------------------------------------------------
// Mask -> bitmask: Mb[b][q][w] bit j = (mask[b][q][w*64+j] != 0)
// One wave produces one u64 via ballot.
// ---------------------------------------------------------------------------
__global__ __launch_bounds__(256)
void mask_bits(const int* __restrict__ mask, unsigned long long* __restrict__ Mb)
{
    const int widx = blockIdx.x * 4 + (threadIdx.x >> 6);
    const int L = threadIdx.x & 63;
    const int m = mask[(size_t)widx * 64 + L];
    unsigned long long bits = __ballot(m != 0);
    if (L == 0) Mb[widx] = bits;
}

// ---------------------------------------------------------------------------
// MFMA GEMM (unchanged from round 3): C = A @ B^T + bias, 128x128 tile, BK=32
// ---------------------------------------------------------------------------
template <bool SPLIT>
__global__ __launch_bounds__(256, 2)
void gemm_mfma(const short* __restrict__ Ahi, const short* __restrict__ Alo,
               const short* __restrict__ Bhi, const short* __restrict__ Blo,
               const float* __restrict__ bias, float* __restrict__ C,
               int M, int N, int K)
{
    __shared__ short AsH[128 * 32];
    __shared__ short BsH[128 * 32];
    __shared__ short AsL[SPLIT ? 128 * 32 : 8];
    __shared__ short BsL[SPLIT ? 128 * 32 : 8];

    const int t = threadIdx.x;
    const int w = t >> 6, L = t & 63;
    const int l16 = L & 15, quad = L >> 4;
    const int wr = w >> 1, wc = w & 1;
    const int bm = blockIdx.x * 128, bn = blockIdx.y * 128;

    const int sm = L >> 2;
    const int sq = ((L & 3) - (sm >> 2)) & 3;
    const int scol = sq * 8;

    f32x4 acc[4][4];
    #pragma unroll
    for (int mi = 0; mi < 4; ++mi)
        #pragma unroll
        for (int ni = 0; ni < 4; ++ni) acc[mi][ni] = (f32x4){0, 0, 0, 0};

    const int fxor = (quad + (l16 >> 2)) & 3;

    for (int k0 = 0; k0 < K; k0 += 32) {
        __syncthreads();
        #pragma unroll
        for (int i = 0; i < 2; ++i) {
            const int wl = w * 2 + i;
            const size_t ra = (size_t)(bm + wl * 16 + sm) * K + k0 + scol;
            const size_t rb = (size_t)(bn + wl * 16 + sm) * K + k0 + scol;
            gload16(Ahi + ra, &AsH[wl * 512]);
            gload16(Bhi + rb, &BsH[wl * 512]);
            if (SPLIT) {
                gload16(Alo + ra, &AsL[wl * 512]);
                gload16(Blo + rb, &BsL[wl * 512]);
            }
        }
        __syncthreads();

        bf16x8 ah[4], bh[4], al[4], bl[4];
        #pragma unroll
        for (int mi = 0; mi < 4; ++mi) {
            const int ch = ((wr * 4 + mi) * 64 + l16 * 4 + fxor) * 8;
            ah[mi] = *(const bf16x8*)&AsH[ch];
            if (SPLIT) al[mi] = *(const bf16x8*)&AsL[ch];
        }
        #pragma unroll
        for (int ni = 0; ni < 4; ++ni) {
            const int ch = ((wc * 4 + ni) * 64 + l16 * 4 + fxor) * 8;
            bh[ni] = *(const bf16x8*)&BsH[ch];
            if (SPLIT) bl[ni] = *(const bf16x8*)&BsL[ch];
        }
        #pragma unroll
        for (int mi = 0; mi < 4; ++mi)
            #pragma unroll
            for (int ni = 0; ni < 4; ++ni) {
                acc[mi][ni] = __builtin_amdgcn_mfma_f32_16x16x32_bf16(
                    ah[mi], bh[ni], acc[mi][ni], 0, 0, 0);
                if (SPLIT) {
                    acc[mi][ni] = __builtin_amdgcn_mfma_f32_16x16x32_bf16(
                        al[mi], bh[ni], acc[mi][ni], 0, 0, 0);
                    acc[mi][ni] = __builtin_amdgcn_mfma_f32_16x16x32_bf16(
                        ah[mi], bl[ni], acc[mi][ni], 0, 0, 0);
                }
            }
    }

    #pragma unroll
    for (int ni = 0; ni < 4; ++ni) {
        const int col = bn + wc * 64 + ni * 16 + l16;
        const float bv = bias[col];
        #pragma unroll
        for (int mi = 0; mi < 4; ++mi) {
            #pragma unroll
            for (int r = 0; r < 4; ++r) {
                const int row = bm + wr * 64 + mi * 16 + quad * 4 + r;
                C[(size_t)row * N + col] = acc[mi][ni][r] + bv;
            }
        }
    }
}

// ---------------------------------------------------------------------------
// RoPE for K: fp32 K2d (B,T,512) -> Khi/Klo bf16 (B,NKV,T,HD)  (unchanged)
// ---------------------------------------------------------------------------
__global__ __launch_bounds__(256)
void rope_k(const float* __restrict__ X2d, short* __restrict__ Khi,
            short* __restrict__ Klo)
{
    const int idx = blockIdx.x * 256 + threadIdx.x;
    const int j  = idx & 63;
    const int tk = (idx >> 6) & (Tc - 1);
    const int kh = (idx >> 17) & (NKVc - 1);
    const int bb = idx >> 19;
    const int row = (kh << 9) + (tk >> 2);
    const int col = ((tk & 3) << 7) + (j << 1);
    const float* src = X2d + ((size_t)bb * Tc + row) * KVEc + col;
    const float a = src[0];
    const float b = src[1];
    const float theta = powf(10000.0f, -(float)j * (1.0f / 64.0f));
    const float ang = (float)tk * theta;
    float s, c;
    sincosf(ang, &s, &c);
    const float r0 = a * c - b * s;
    const float r1 = a * s + b * c;
    const size_t off = (((size_t)bb * NKVc + kh) * Tc + tk) * HDc + (j << 1);
    short h0 = f2bf(r0), h1 = f2bf(r1);
    Khi[off]     = h0;  Klo[off]     = f2bf(r0 - bf2f(h0));
    Khi[off + 1] = h1;  Klo[off + 1] = f2bf(r1 - bf2f(h1));
}

// ---------------------------------------------------------------------------
// RoPE for V fused with transpose (unchanged): V2d -> Vt bf16 (B,NKV,HD,T)
// ---------------------------------------------------------------------------
__global__ __launch_bounds__(256)
void rope_v_t(const float* __restrict__ V2d, short* __restrict__ Vt)
{
    __shared__ short Ls[128][40];
    const int g  = blockIdx.x;
    const int kh = blockIdx.y;
    const int bb = blockIdx.z;
    const int t  = threadIdx.x;

    const float* src = V2d + ((size_t)bb * Tc + (kh << 9) + (g << 3)) * KVEc;
    #pragma unroll
    for (int i = 0; i < 4; ++i) {
        int e = i * 256 + t;
        float4 v = ((const float4*)src)[e];
        int row = e >> 7;
        int col = (e & 127) << 2;
        int tkl = (row << 2) + (col >> 7);
        int d0  = col & 127;
        int tk  = (g << 5) + tkl;
        float fv[4] = {v.x, v.y, v.z, v.w};
        #pragma unroll
        for (int p = 0; p < 2; ++p) {
            int j = (d0 >> 1) + p;
            float theta = powf(10000.0f, -(float)j * (1.0f / 64.0f));
            float ang = (float)tk * theta;
            float s, c;
            sincosf(ang, &s, &c);
            float a = fv[2 * p], b = fv[2 * p + 1];
            Ls[d0 + 2 * p    ][tkl] = f2bf(a * c - b * s);
            Ls[d0 + 2 * p + 1][tkl] = f2bf(a * s + b * c);
        }
    }
    __syncthreads();
    const int d = t >> 1;
    const int h16 = (t & 1) << 4;
    short* dst = Vt + (((size_t)bb * NKVc + kh) * HDc + d) * Tc + (g << 5) + h16;
    bf16x8 o0 = *(const bf16x8*)&Ls[d][h16];
    bf16x8 o1 = *(const bf16x8*)&Ls[d][h16 + 8];
    *(bf16x8*)dst = o0;
    *(bf16x8*)(dst + 8) = o1;
}

// ---------------------------------------------------------------------------
// MFMA flash attention, 512 threads = 8 waves x 16 q-rows (128 q per block).
// K-tiles of 64 keys (one u64 mask word per (q,kt)).
// Bitmask mask; deferred l-reduction; conditional O-rescale.
// ---------------------------------------------------------------------------
__global__ __launch_bounds__(512, 4)
void attn_mfma(const float* __restrict__ Q2d, const short* __restrict__ Khi_g,
               const short* __restrict__ Klo_g, const short* __restrict__ Vt_g,
               const unsigned long long* __restrict__ Mb, short* __restrict__ AObf)
{
    constexpr int SP = 72;
    __shared__ short KhiS[64 * 128];
    __shared__ short KloS[64 * 128];
    __shared__ short VtS [128 * 64];
    __shared__ short Ps  [128 * SP];

    const int qb = blockIdx.x;   // 0..15 (128-q block)
    const int h  = blockIdx.y;   // 0..15
    const int bb = blockIdx.z;   // 0..3
    const int t  = threadIdx.x;
    const int w    = t >> 6;     // wave 0..7
    const int L    = t & 63;
    const int l16  = L & 15;
    const int quad = L >> 4;
    const int kh   = h & (NKVc - 1);     // jnp.tile: head h -> kv-head h%4
    const int tq0  = qb * 128 + w * 16;

    // ---- Q fragments (hi/lo split) from fp32 Q2d, loaded once ----
    // tq = tq0+l16 -> Q2d row = h*128 + qb*8 + w, col = 128*l16 + d
    bf16x8 qhi[4], qlo[4];
    {
        const float* qrow = Q2d +
            ((size_t)(bb * Tc + h * HDc + qb * 8 + w)) * Ec + 128 * l16;
        #pragma unroll
        for (int kc = 0; kc < 4; ++kc) {
            const float* p = qrow + kc * 32 + quad * 8;
            #pragma unroll
            for (int j = 0; j < 8; ++j) {
                float f = p[j];
                short hi = f2bf(f);
                qhi[kc][j] = hi;
                qlo[kc][j] = f2bf(f - bf2f(hi));
            }
        }
    }

    float m_r[4], lp[4];
    #pragma unroll
    for (int r = 0; r < 4; ++r) { m_r[r] = -INFINITY; lp[r] = 0.0f; }
    f32x4 o[8];
    #pragma unroll
    for (int nc = 0; nc < 8; ++nc) o[nc] = (f32x4){0, 0, 0, 0};

    const short* kbh = Khi_g + ((size_t)(bb * NKVc + kh)) * Tc * HDc;
    const short* kbl = Klo_g + ((size_t)(bb * NKVc + kh)) * Tc * HDc;
    const short* vb  = Vt_g  + ((size_t)(bb * NKVc + kh)) * HDc * Tc;
    const unsigned long long* mrow0 =
        Mb + ((size_t)(bb * Tc + tq0 + quad * 4)) * (Tc / 64);
    const float scale = 11.313708498984761f;  // sqrt(128)

    // staging lane decode
    const int km   = L >> 4;
    const int kpos = L & 15;
    const int vm   = L >> 3;
    const int vc   = ((L & 7) - vm) & 7;

    for (int kt = 0; kt < Tc / 64; ++kt) {
        // mask words: one u64 per q-row covers this tile's 64 keys
        unsigned long long mw[4];
        #pragma unroll
        for (int r = 0; r < 4; ++r)
            mw[r] = mrow0[(size_t)r * (Tc / 64) + kt];

        __syncthreads();   // previous tile's LDS reads complete

        // ---- stage K hi/lo + V^T via DMA (wave w does wl = 2w, 2w+1) ----
        #pragma unroll
        for (int i = 0; i < 2; ++i) {
            const int wl = w * 2 + i;
            const int krow = wl * 4 + km;
            const int kc_ = (kpos - (krow & 15)) & 15;
            const size_t go = (size_t)(kt * 64 + krow) * HDc + kc_ * 8;
            gload16(kbh + go, &KhiS[wl * 512]);
            gload16(kbl + go, &KloS[wl * 512]);
            const int vrow = wl * 8 + vm;
            gload16(vb + (size_t)vrow * Tc + kt * 64 + vc * 8, &VtS[wl * 512]);
        }
        __syncthreads();   // loads drained

        // ---- QK^T: S(16q x 64k), split-bf16 (3 MFMA) ----
        f32x4 s[4];
        #pragma unroll
        for (int nt = 0; nt < 4; ++nt) {
            f32x4 acc = (f32x4){0, 0, 0, 0};
            #pragma unroll
            for (int kc = 0; kc < 4; ++kc) {
                const int ch = (((nt * 4 + (l16 >> 2)) << 6) + ((l16 & 3) << 4)
                                + ((kc * 4 + quad + l16) & 15)) << 3;
                bf16x8 khiF = *(const bf16x8*)&KhiS[ch];
                bf16x8 kloF = *(const bf16x8*)&KloS[ch];
                acc = __builtin_amdgcn_mfma_f32_16x16x32_bf16(qhi[kc], khiF, acc, 0, 0, 0);
                acc = __builtin_amdgcn_mfma_f32_16x16x32_bf16(qlo[kc], khiF, acc, 0, 0, 0);
                acc = __builtin_amdgcn_mfma_f32_16x16x32_bf16(qhi[kc], kloF, acc, 0, 0, 0);
            }
            s[nt] = acc;
        }

        // ---- scale + mask via bit tests (bit nt*16+l16 of mw[r]) ----
        #pragma unroll
        for (int r = 0; r < 4; ++r) {
            const unsigned t0 = (unsigned)(mw[r] >> l16);
            const unsigned t1 = (unsigned)(mw[r] >> (l16 + 32));
            s[0][r] = (t0 & 1u)       ? s[0][r] * scale : 1e-9f;
            s[1][r] = (t0 & 0x10000u) ? s[1][r] * scale : 1e-9f;
            s[2][r] = (t1 & 1u)       ? s[2][r] * scale : 1e-9f;
            s[3][r] = (t1 & 0x10000u) ? s[3][r] * scale : 1e-9f;
        }

        // ---- online softmax: max reduce across 16-lane group ----
        float mt[4];
        #pragma unroll
        for (int r = 0; r < 4; ++r)
            mt[r] = fmaxf(fmaxf(s[0][r], s[1][r]), fmaxf(s[2][r], s[3][r]));
        #pragma unroll
        for (int off = 1; off < 16; off <<= 1)
            #pragma unroll
            for (int r = 0; r < 4; ++r)
                mt[r] = fmaxf(mt[r], __shfl_xor(mt[r], off));

        float al[4];
        bool need = false;
        #pragma unroll
        for (int r = 0; r < 4; ++r) {
            const float mn = fmaxf(m_r[r], mt[r]);
            al[r] = __expf(m_r[r] - mn);   // ==1.0 iff max unchanged
            need |= (al[r] < 1.0f);
            m_r[r] = mn;
        }

        // p = exp(s - m); per-lane partial row sums (al is group-uniform)
        float rsum[4];
        #pragma unroll
        for (int r = 0; r < 4; ++r) {
            float p0 = __expf(s[0][r] - m_r[r]);
            float p1 = __expf(s[1][r] - m_r[r]);
            float p2 = __expf(s[2][r] - m_r[r]);
            float p3 = __expf(s[3][r] - m_r[r]);
            s[0][r] = p0; s[1][r] = p1; s[2][r] = p2; s[3][r] = p3;
            rsum[r] = (p0 + p1) + (p2 + p3);
        }

        // conditional rescale of O and l partials (skipped when max unchanged)
        if (__any(need)) {
            #pragma unroll
            for (int r = 0; r < 4; ++r) lp[r] *= al[r];
            #pragma unroll
            for (int nc = 0; nc < 8; ++nc)
                #pragma unroll
                for (int r = 0; r < 4; ++r)
                    o[nc][r] *= al[r];
        }
        #pragma unroll
        for (int r = 0; r < 4; ++r) lp[r] += rsum[r];

        // ---- P: C-layout -> LDS -> A-layout (wave-private rows) ----
        #pragma unroll
        for (int nt = 0; nt < 4; ++nt)
            #pragma unroll
            for (int r = 0; r < 4; ++r)
                Ps[(w * 16 + quad * 4 + r) * SP + nt * 16 + l16] = f2bf(s[nt][r]);

        bf16x8 a0 = *(const bf16x8*)&Ps[(w * 16 + l16) * SP + quad * 8];
        bf16x8 a1 = *(const bf16x8*)&Ps[(w * 16 + l16) * SP + 32 + quad * 8];

        // ---- PV: O(16q x 128d) += P . V ----
        #pragma unroll
        for (int nc = 0; nc < 8; ++nc) {
            const int rg = (nc * 2 + (l16 >> 3)) << 6;
            const int rm = l16 & 7;
            const int ch0 = (rg + (rm << 3) + ((quad + rm) & 7)) << 3;
            const int ch1 = (rg + (rm << 3) + ((quad + 4 + rm) & 7)) << 3;
            bf16x8 b0 = *(const bf16x8*)&VtS[ch0];
            bf16x8 b1 = *(const bf16x8*)&VtS[ch1];
            o[nc] = __builtin_amdgcn_mfma_f32_16x16x32_bf16(a0, b0, o[nc], 0, 0, 0);
            o[nc] = __builtin_amdgcn_mfma_f32_16x16x32_bf16(a1, b1, o[nc], 0, 0, 0);
        }
    }

    // ---- final l reduction across the 16-lane group ----
    #pragma unroll
    for (int off = 1; off < 16; off <<= 1)
        #pragma unroll
        for (int r = 0; r < 4; ++r)
            lp[r] += __shfl_xor(lp[r], off);

    float inv[4];
    #pragma unroll
    for (int r = 0; r < 4; ++r) inv[r] = 1.0f / lp[r];
    #pragma unroll
    for (int r = 0; r < 4; ++r) {
        short* orow = AObf + ((size_t)(bb * Tc + tq0 + quad * 4 + r)) * Ec
                           + h * HDc + l16;
        #pragma unroll
        for (int nc = 0; nc < 8; ++nc)
            orow[nc * 16] = f2bf(o[nc][r] * inv[r]);
    }
}

// ---------------------------------------------------------------------------
// Launch
// ---------------------------------------------------------------------------
extern "C" void kernel_launch(void* const* d_in, const int* in_sizes, int n_in,
                              void* d_out, int out_size, void* d_ws, size_t ws_size,
                              hipStream_t stream)
{
    const float* x    = (const float*)d_in[0];
    const int*  amask = (const int*)  d_in[1];
    const float* Wq   = (const float*)d_in[2];
    const float* bq   = (const float*)d_in[3];
    const float* Wk   = (const float*)d_in[4];
    const float* bk   = (const float*)d_in[5];
    const float* Wv   = (const float*)d_in[6];
    const float* bv   = (const float*)d_in[7];
    const float* Wo   = (const float*)d_in[8];
    const float* bo   = (const float*)d_in[9];
    float* out = (float*)d_out;

    // Workspace layout (bytes), 160 MiB + 2 MiB bitmask:
    //  [0,   64M)  Q2d fp32
    //  [64M, 96M)  Xhi bf16            -> AObf bf16 (after V-GEMM)
    //  [96M,128M)  Xlo bf16            -> V2d fp32 [96M,112M) + Khi/Klo [112M,128M)
    //  [128M,144M) WqT hi+lo           -> WkT hi/lo + WvT + WoT (after Q-GEMM)
    //  [144M,160M) K2d fp32            -> Vt bf16 (after rope_k)
    //  [160M,162M) Mbits u64
    char* ws = (char*)d_ws;
    float* Q2d   = (float*)(ws);
    short* Xhi   = (short*)(ws + 67108864);
    short* Xlo   = (short*)(ws + 100663296);
    short* WqThi = (short*)(ws + 134217728);
    short* WqTlo = (short*)(ws + 134217728 + 8388608);
    float* K2d   = (float*)(ws + 150994944);
    // overlays:
    float* V2d   = (float*)(ws + 100663296);              // over Xlo[0:16M)
    short* Khi   = (short*)(ws + 100663296 + 16777216);   // over Xlo[16M:24M)
    short* Klo   = (short*)(ws + 100663296 + 25165824);   // over Xlo[24M:32M)
    short* WkThi = (short*)(ws + 134217728);              // over WqT after Q-GEMM
    short* WkTlo = (short*)(ws + 134217728 + 2097152);
    short* WvThi = (short*)(ws + 134217728 + 4194304);
    short* WoThi = (short*)(ws + 134217728 + 8388608);
    short* Vt    = (short*)(ws + 150994944);              // over K2d after rope_k
    short* AObf  = (short*)(ws + 67108864);               // over Xhi after V-GEMM
    unsigned long long* Mb = (unsigned long long*)(ws + 167772160);

    const int M = Bc * Tc;      // 8192
    dim3 blk(256);

    // 0) mask -> bitmask (B*T*T/64 = 262144 words, 4 words/block)
    mask_bits<<<(Bc * Tc * (Tc / 64)) / 4, blk, 0, stream>>>(amask, Mb);
    // 1) Wq^T split, x split
    transpose_split<<<dim3(Ec / 32, Ec / 32), blk, 0, stream>>>(Wq, WqThi, WqTlo, Ec, Ec);
    convert_split<<<(M * Ec / 4) / 256, blk, 0, stream>>>(x, Xhi, Xlo);
    // 2) Q projection (split, fp32-fidelity)
    gemm_mfma<true><<<dim3(M / 128, Ec / 128), blk, 0, stream>>>(
        Xhi, Xlo, WqThi, WqTlo, bq, Q2d, M, Ec, Ec);
    // 3) remaining weight transposes (into the now-dead WqT slab)
    transpose_split<<<dim3(Ec / 32, KVEc / 32), blk, 0, stream>>>(Wk, WkThi, WkTlo, Ec, KVEc);
    transpose_split<<<dim3(Ec / 32, KVEc / 32), blk, 0, stream>>>(Wv, WvThi, nullptr, Ec, KVEc);
    transpose_split<<<dim3(Ec / 32, Ec / 32), blk, 0, stream>>>(Wo, WoThi, nullptr, Ec, Ec);
    // 4) K projection (split), V projection (plain)
    gemm_mfma<true><<<dim3(M / 128, KVEc / 128), blk, 0, stream>>>(
        Xhi, Xlo, WkThi, WkTlo, bk, K2d, M, KVEc, Ec);
    gemm_mfma<false><<<dim3(M / 128, KVEc / 128), blk, 0, stream>>>(
        Xhi, nullptr, WvThi, nullptr, bv, V2d, M, KVEc, Ec);
    // 5) RoPE: K -> hi/lo bf16, V -> transposed bf16
    rope_k<<<(Bc * NKVc * Tc * 64) / 256, blk, 0, stream>>>(K2d, Khi, Klo);
    rope_v_t<<<dim3(Tc / 32, NKVc, Bc), blk, 0, stream>>>(V2d, Vt);
    // 6) attention (512 threads, 128 q-rows/block) -> bf16 AO
    attn_mfma<<<dim3(Tc / 128, NHc, Bc), dim3(512), 0, stream>>>(
        Q2d, Khi, Klo, Vt, Mb, AObf);
    // 7) output projection (plain)
    gemm_mfma<false><<<dim3(M / 128, Ec / 128), blk, 0, stream>>>(
        AObf, nullptr, WoThi, nullptr, bo, out, M, Ec, Ec);
}

// Round 5
// 1083.090 us; speedup vs baseline: 1.5987x; 1.5987x over previous
//
#include <hip/hip_runtime.h>
#include <math.h>

// Problem constants (B,T,E)=(4,2048,2048), NH=16, NKV=4, HD=128
constexpr int Bc   = 4;
constexpr int Tc   = 2048;
constexpr int Ec   = 2048;
constexpr int NHc  = 16;
constexpr int NKVc = 4;
constexpr int HDc  = 128;
constexpr int KVEc = NKVc * HDc; // 512

typedef __attribute__((ext_vector_type(8))) short bf16x8;
typedef __attribute__((ext_vector_type(4))) short short4v;
typedef __attribute__((ext_vector_type(4))) float f32x4;

__device__ __forceinline__ short f2bf(float f) {   // round-to-nearest-even
    union { float f; unsigned u; } v; v.f = f;
    unsigned r = v.u + 0x7FFF + ((v.u >> 16) & 1);
    return (short)(r >> 16);
}
__device__ __forceinline__ float bf2f(short s) {
    union { unsigned u; float f; } v; v.u = ((unsigned)(unsigned short)s) << 16;
    return v.f;
}
// async global->LDS, 16B per lane; LDS dest = wave-uniform base + lane*16
__device__ __forceinline__ void gload16(const void* g, void* l) {
    __builtin_amdgcn_global_load_lds(
        (const __attribute__((address_space(1))) unsigned*)g,
        (__attribute__((address_space(3))) unsigned*)l, 16, 0, 0);
}

// ---------------------------------------------------------------------------
// Prep: x fp32 -> hi/lo bf16 (same layout)
// ---------------------------------------------------------------------------
__global__ __launch_bounds__(256)
void convert_split(const float* __restrict__ X, short* __restrict__ Xhi,
                   short* __restrict__ Xlo)
{
    int i = blockIdx.x * 256 + threadIdx.x;    // float4 index
    float4 v = ((const float4*)X)[i];
    float fv[4] = {v.x, v.y, v.z, v.w};
    short4v hi, lo;
    #pragma unroll
    for (int j = 0; j < 4; ++j) {
        hi[j] = f2bf(fv[j]);
        lo[j] = f2bf(fv[j] - bf2f(hi[j]));
    }
    ((short4v*)Xhi)[i] = hi;
    ((short4v*)Xlo)[i] = lo;
}

// ---------------------------------------------------------------------------
// Prep: W [K][N] fp32 -> WT hi (and optional lo) [N][K] bf16
// ---------------------------------------------------------------------------
__global__ __launch_bounds__(256)
void transpose_split(const float* __restrict__ W, short* __restrict__ WThi,
                     short* __restrict__ WTlo, int K, int N)
{
    __shared__ float Ls[32][33];
    const int k0 = blockIdx.x * 32, n0 = blockIdx.y * 32;
    const int t = threadIdx.x;
    const int r = t >> 3, c4 = (t & 7) << 2;
    float4 v = *(const float4*)(W + (size_t)(k0 + r) * N + n0 + c4);
    Ls[r][c4 + 0] = v.x; Ls[r][c4 + 1] = v.y;
    Ls[r][c4 + 2] = v.z; Ls[r][c4 + 3] = v.w;
    __syncthreads();
    short4v hi, lo;
    #pragma unroll
    for (int i = 0; i < 4; ++i) {
        float f = Ls[c4 + i][r];
        hi[i] = f2bf(f);
        lo[i] = f2bf(f - bf2f(hi[i]));
    }
    *(short4v*)(WThi + (size_t)(n0 + r) * K + k0 + c4) = hi;
    if (WTlo) *(short4v*)(WTlo + (size_t)(n0 + r) * K + k0 + c4) = lo;
}

// ---------------------------------------------------------------------------
// Mask -> bitmask: Mb[b][q][w] bit j = (mask[b][q][w*64+j] != 0)
// ---------------------------------------------------------------------------
__global__ __launch_bounds__(256)
void mask_bits(const int* __restrict__ mask, unsigned long long* __restrict__ Mb)
{
    const int widx = blockIdx.x * 4 + (threadIdx.x >> 6);
    const int L = threadIdx.x & 63;
    const int m = mask[(size_t)widx * 64 + L];
    unsigned long long bits = __ballot(m != 0);
    if (L == 0) Mb[widx] = bits;
}

// ---------------------------------------------------------------------------
// MFMA GEMM (unchanged): C = A @ B^T + bias, 128x128 tile, BK=32
// ---------------------------------------------------------------------------
template <bool SPLIT>
__global__ __launch_bounds__(256, 2)
void gemm_mfma(const short* __restrict__ Ahi, const short* __restrict__ Alo,
               const short* __restrict__ Bhi, const short* __restrict__ Blo,
               const float* __restrict__ bias, float* __restrict__ C,
               int M, int N, int K)
{
    __shared__ short AsH[128 * 32];
    __shared__ short BsH[128 * 32];
    __shared__ short AsL[SPLIT ? 128 * 32 : 8];
    __shared__ short BsL[SPLIT ? 128 * 32 : 8];

    const int t = threadIdx.x;
    const int w = t >> 6, L = t & 63;
    const int l16 = L & 15, quad = L >> 4;
    const int wr = w >> 1, wc = w & 1;
    const int bm = blockIdx.x * 128, bn = blockIdx.y * 128;

    const int sm = L >> 2;
    const int sq = ((L & 3) - (sm >> 2)) & 3;
    const int scol = sq * 8;

    f32x4 acc[4][4];
    #pragma unroll
    for (int mi = 0; mi < 4; ++mi)
        #pragma unroll
        for (int ni = 0; ni < 4; ++ni) acc[mi][ni] = (f32x4){0, 0, 0, 0};

    const int fxor = (quad + (l16 >> 2)) & 3;

    for (int k0 = 0; k0 < K; k0 += 32) {
        __syncthreads();
        #pragma unroll
        for (int i = 0; i < 2; ++i) {
            const int wl = w * 2 + i;
            const size_t ra = (size_t)(bm + wl * 16 + sm) * K + k0 + scol;
            const size_t rb = (size_t)(bn + wl * 16 + sm) * K + k0 + scol;
            gload16(Ahi + ra, &AsH[wl * 512]);
            gload16(Bhi + rb, &BsH[wl * 512]);
            if (SPLIT) {
                gload16(Alo + ra, &AsL[wl * 512]);
                gload16(Blo + rb, &BsL[wl * 512]);
            }
        }
        __syncthreads();

        bf16x8 ah[4], bh[4], al[4], bl[4];
        #pragma unroll
        for (int mi = 0; mi < 4; ++mi) {
            const int ch = ((wr * 4 + mi) * 64 + l16 * 4 + fxor) * 8;
            ah[mi] = *(const bf16x8*)&AsH[ch];
            if (SPLIT) al[mi] = *(const bf16x8*)&AsL[ch];
        }
        #pragma unroll
        for (int ni = 0; ni < 4; ++ni) {
            const int ch = ((wc * 4 + ni) * 64 + l16 * 4 + fxor) * 8;
            bh[ni] = *(const bf16x8*)&BsH[ch];
            if (SPLIT) bl[ni] = *(const bf16x8*)&BsL[ch];
        }
        #pragma unroll
        for (int mi = 0; mi < 4; ++mi)
            #pragma unroll
            for (int ni = 0; ni < 4; ++ni) {
                acc[mi][ni] = __builtin_amdgcn_mfma_f32_16x16x32_bf16(
                    ah[mi], bh[ni], acc[mi][ni], 0, 0, 0);
                if (SPLIT) {
                    acc[mi][ni] = __builtin_amdgcn_mfma_f32_16x16x32_bf16(
                        al[mi], bh[ni], acc[mi][ni], 0, 0, 0);
                    acc[mi][ni] = __builtin_amdgcn_mfma_f32_16x16x32_bf16(
                        ah[mi], bl[ni], acc[mi][ni], 0, 0, 0);
                }
            }
    }

    #pragma unroll
    for (int ni = 0; ni < 4; ++ni) {
        const int col = bn + wc * 64 + ni * 16 + l16;
        const float bv = bias[col];
        #pragma unroll
        for (int mi = 0; mi < 4; ++mi) {
            #pragma unroll
            for (int r = 0; r < 4; ++r) {
                const int row = bm + wr * 64 + mi * 16 + quad * 4 + r;
                C[(size_t)row * N + col] = acc[mi][ni][r] + bv;
            }
        }
    }
}

// ---------------------------------------------------------------------------
// RoPE for K: fp32 K2d (B,T,512) -> Khi/Klo bf16 (B,NKV,T,HD)  (unchanged)
// ---------------------------------------------------------------------------
__global__ __launch_bounds__(256)
void rope_k(const float* __restrict__ X2d, short* __restrict__ Khi,
            short* __restrict__ Klo)
{
    const int idx = blockIdx.x * 256 + threadIdx.x;
    const int j  = idx & 63;
    const int tk = (idx >> 6) & (Tc - 1);
    const int kh = (idx >> 17) & (NKVc - 1);
    const int bb = idx >> 19;
    const int row = (kh << 9) + (tk >> 2);
    const int col = ((tk & 3) << 7) + (j << 1);
    const float* src = X2d + ((size_t)bb * Tc + row) * KVEc + col;
    const float a = src[0];
    const float b = src[1];
    const float theta = powf(10000.0f, -(float)j * (1.0f / 64.0f));
    const float ang = (float)tk * theta;
    float s, c;
    sincosf(ang, &s, &c);
    const float r0 = a * c - b * s;
    const float r1 = a * s + b * c;
    const size_t off = (((size_t)bb * NKVc + kh) * Tc + tk) * HDc + (j << 1);
    short h0 = f2bf(r0), h1 = f2bf(r1);
    Khi[off]     = h0;  Klo[off]     = f2bf(r0 - bf2f(h0));
    Khi[off + 1] = h1;  Klo[off + 1] = f2bf(r1 - bf2f(h1));
}

// ---------------------------------------------------------------------------
// RoPE for V fused with transpose (unchanged): V2d -> Vt bf16 (B,NKV,HD,T)
// ---------------------------------------------------------------------------
__global__ __launch_bounds__(256)
void rope_v_t(const float* __restrict__ V2d, short* __restrict__ Vt)
{
    __shared__ short Ls[128][40];
    const int g  = blockIdx.x;
    const int kh = blockIdx.y;
    const int bb = blockIdx.z;
    const int t  = threadIdx.x;

    const float* src = V2d + ((size_t)bb * Tc + (kh << 9) + (g << 3)) * KVEc;
    #pragma unroll
    for (int i = 0; i < 4; ++i) {
        int e = i * 256 + t;
        float4 v = ((const float4*)src)[e];
        int row = e >> 7;
        int col = (e & 127) << 2;
        int tkl = (row << 2) + (col >> 7);
        int d0  = col & 127;
        int tk  = (g << 5) + tkl;
        float fv[4] = {v.x, v.y, v.z, v.w};
        #pragma unroll
        for (int p = 0; p < 2; ++p) {
            int j = (d0 >> 1) + p;
            float theta = powf(10000.0f, -(float)j * (1.0f / 64.0f));
            float ang = (float)tk * theta;
            float s, c;
            sincosf(ang, &s, &c);
            float a = fv[2 * p], b = fv[2 * p + 1];
            Ls[d0 + 2 * p    ][tkl] = f2bf(a * c - b * s);
            Ls[d0 + 2 * p + 1][tkl] = f2bf(a * s + b * c);
        }
    }
    __syncthreads();
    const int d = t >> 1;
    const int h16 = (t & 1) << 4;
    short* dst = Vt + (((size_t)bb * NKVc + kh) * HDc + d) * Tc + (g << 5) + h16;
    bf16x8 o0 = *(const bf16x8*)&Ls[d][h16];
    bf16x8 o1 = *(const bf16x8*)&Ls[d][h16 + 8];
    *(bf16x8*)dst = o0;
    *(bf16x8*)(dst + 8) = o1;
}

// ---------------------------------------------------------------------------
// MFMA flash attention — R3 execution shape (256 thr, 4 waves, VGPR budget
// for 2 waves/EU so no spills) + R4 algorithmic wins (bitmask mask, deferred
// l-reduction, conditional O-rescale).
// ---------------------------------------------------------------------------
__global__ __launch_bounds__(256, 2)
void attn_mfma(const float* __restrict__ Q2d, const short* __restrict__ Khi_g,
               const short* __restrict__ Klo_g, const short* __restrict__ Vt_g,
               const unsigned long long* __restrict__ Mb, short* __restrict__ AObf)
{
    constexpr int SP = 72;
    __shared__ short KhiS[64 * 128];
    __shared__ short KloS[64 * 128];
    __shared__ short VtS [128 * 64];
    __shared__ short Ps  [64 * SP];

    const int qb = blockIdx.x;   // 0..31 (64-q block)
    const int h  = blockIdx.y;   // 0..15
    const int bb = blockIdx.z;   // 0..3
    const int t  = threadIdx.x;
    const int w    = t >> 6;     // wave 0..3
    const int L    = t & 63;
    const int l16  = L & 15;
    const int quad = L >> 4;
    const int kh   = h & (NKVc - 1);     // jnp.tile: head h -> kv-head h%4
    const int tq0  = qb * 64 + w * 16;

    // ---- Q fragments (hi/lo split) from fp32 Q2d, loaded once ----
    bf16x8 qhi[4], qlo[4];
    {
        const float* qrow = Q2d +
            ((size_t)(bb * Tc + h * HDc + qb * 4 + w)) * Ec + 128 * l16;
        #pragma unroll
        for (int kc = 0; kc < 4; ++kc) {
            const float* p = qrow + kc * 32 + quad * 8;
            #pragma unroll
            for (int j = 0; j < 8; ++j) {
                float f = p[j];
                short hi = f2bf(f);
                qhi[kc][j] = hi;
                qlo[kc][j] = f2bf(f - bf2f(hi));
            }
        }
    }

    float m_r[4], lp[4];
    #pragma unroll
    for (int r = 0; r < 4; ++r) { m_r[r] = -INFINITY; lp[r] = 0.0f; }
    f32x4 o[8];
    #pragma unroll
    for (int nc = 0; nc < 8; ++nc) o[nc] = (f32x4){0, 0, 0, 0};

    const short* kbh = Khi_g + ((size_t)(bb * NKVc + kh)) * Tc * HDc;
    const short* kbl = Klo_g + ((size_t)(bb * NKVc + kh)) * Tc * HDc;
    const short* vb  = Vt_g  + ((size_t)(bb * NKVc + kh)) * HDc * Tc;
    const unsigned long long* mrow0 =
        Mb + ((size_t)(bb * Tc + tq0 + quad * 4)) * (Tc / 64);
    const float scale = 11.313708498984761f;  // sqrt(128)

    // staging lane decode
    const int km   = L >> 4;
    const int kpos = L & 15;
    const int vm   = L >> 3;
    const int vc   = ((L & 7) - vm) & 7;

    for (int kt = 0; kt < Tc / 64; ++kt) {
        // mask words: one u64 per q-row covers this tile's 64 keys
        unsigned long long mw[4];
        #pragma unroll
        for (int r = 0; r < 4; ++r)
            mw[r] = mrow0[(size_t)r * (Tc / 64) + kt];

        __syncthreads();   // previous tile's LDS reads complete

        // ---- stage K hi/lo + V^T via DMA (wave w does wl = 4w..4w+3) ----
        #pragma unroll
        for (int i = 0; i < 4; ++i) {
            const int wl = w * 4 + i;
            const int krow = wl * 4 + km;
            const int kc_ = (kpos - (krow & 15)) & 15;
            const size_t go = (size_t)(kt * 64 + krow) * HDc + kc_ * 8;
            gload16(kbh + go, &KhiS[wl * 512]);
            gload16(kbl + go, &KloS[wl * 512]);
            const int vrow = wl * 8 + vm;
            gload16(vb + (size_t)vrow * Tc + kt * 64 + vc * 8, &VtS[wl * 512]);
        }
        __syncthreads();   // loads drained

        // ---- QK^T: S(16q x 64k), split-bf16 (3 MFMA) ----
        f32x4 s[4];
        #pragma unroll
        for (int nt = 0; nt < 4; ++nt) {
            f32x4 acc = (f32x4){0, 0, 0, 0};
            #pragma unroll
            for (int kc = 0; kc < 4; ++kc) {
                const int ch = (((nt * 4 + (l16 >> 2)) << 6) + ((l16 & 3) << 4)
                                + ((kc * 4 + quad + l16) & 15)) << 3;
                bf16x8 khiF = *(const bf16x8*)&KhiS[ch];
                bf16x8 kloF = *(const bf16x8*)&KloS[ch];
                acc = __builtin_amdgcn_mfma_f32_16x16x32_bf16(qhi[kc], khiF, acc, 0, 0, 0);
                acc = __builtin_amdgcn_mfma_f32_16x16x32_bf16(qlo[kc], khiF, acc, 0, 0, 0);
                acc = __builtin_amdgcn_mfma_f32_16x16x32_bf16(qhi[kc], kloF, acc, 0, 0, 0);
            }
            s[nt] = acc;
        }

        // ---- scale + mask via bit tests (bit nt*16+l16 of mw[r]) ----
        #pragma unroll
        for (int r = 0; r < 4; ++r) {
            const unsigned t0 = (unsigned)(mw[r] >> l16);
            const unsigned t1 = (unsigned)(mw[r] >> (l16 + 32));
            s[0][r] = (t0 & 1u)       ? s[0][r] * scale : 1e-9f;
            s[1][r] = (t0 & 0x10000u) ? s[1][r] * scale : 1e-9f;
            s[2][r] = (t1 & 1u)       ? s[2][r] * scale : 1e-9f;
            s[3][r] = (t1 & 0x10000u) ? s[3][r] * scale : 1e-9f;
        }

        // ---- online softmax: max reduce across 16-lane group ----
        float mt[4];
        #pragma unroll
        for (int r = 0; r < 4; ++r)
            mt[r] = fmaxf(fmaxf(s[0][r], s[1][r]), fmaxf(s[2][r], s[3][r]));
        #pragma unroll
        for (int off = 1; off < 16; off <<= 1)
            #pragma unroll
            for (int r = 0; r < 4; ++r)
                mt[r] = fmaxf(mt[r], __shfl_xor(mt[r], off));

        float al[4];
        bool need = false;
        #pragma unroll
        for (int r = 0; r < 4; ++r) {
            const float mn = fmaxf(m_r[r], mt[r]);
            al[r] = __expf(m_r[r] - mn);   // ==1.0 iff max unchanged
            need |= (al[r] < 1.0f);
            m_r[r] = mn;
        }

        // p = exp(s - m); per-lane partial row sums (al is group-uniform)
        float rsum[4];
        #pragma unroll
        for (int r = 0; r < 4; ++r) {
            float p0 = __expf(s[0][r] - m_r[r]);
            float p1 = __expf(s[1][r] - m_r[r]);
            float p2 = __expf(s[2][r] - m_r[r]);
            float p3 = __expf(s[3][r] - m_r[r]);
            s[0][r] = p0; s[1][r] = p1; s[2][r] = p2; s[3][r] = p3;
            rsum[r] = (p0 + p1) + (p2 + p3);
        }

        // conditional rescale of O and l partials (skipped when max unchanged)
        if (__any(need)) {
            #pragma unroll
            for (int r = 0; r < 4; ++r) lp[r] *= al[r];
            #pragma unroll
            for (int nc = 0; nc < 8; ++nc)
                #pragma unroll
                for (int r = 0; r < 4; ++r)
                    o[nc][r] *= al[r];
        }
        #pragma unroll
        for (int r = 0; r < 4; ++r) lp[r] += rsum[r];

        // ---- P: C-layout -> LDS -> A-layout (wave-private rows) ----
        #pragma unroll
        for (int nt = 0; nt < 4; ++nt)
            #pragma unroll
            for (int r = 0; r < 4; ++r)
                Ps[(w * 16 + quad * 4 + r) * SP + nt * 16 + l16] = f2bf(s[nt][r]);

        bf16x8 a0 = *(const bf16x8*)&Ps[(w * 16 + l16) * SP + quad * 8];
        bf16x8 a1 = *(const bf16x8*)&Ps[(w * 16 + l16) * SP + 32 + quad * 8];

        // ---- PV: O(16q x 128d) += P . V ----
        #pragma unroll
        for (int nc = 0; nc < 8; ++nc) {
            const int rg = (nc * 2 + (l16 >> 3)) << 6;
            const int rm = l16 & 7;
            const int ch0 = (rg + (rm << 3) + ((quad + rm) & 7)) << 3;
            const int ch1 = (rg + (rm << 3) + ((quad + 4 + rm) & 7)) << 3;
            bf16x8 b0 = *(const bf16x8*)&VtS[ch0];
            bf16x8 b1 = *(const bf16x8*)&VtS[ch1];
            o[nc] = __builtin_amdgcn_mfma_f32_16x16x32_bf16(a0, b0, o[nc], 0, 0, 0);
            o[nc] = __builtin_amdgcn_mfma_f32_16x16x32_bf16(a1, b1, o[nc], 0, 0, 0);
        }
    }

    // ---- final l reduction across the 16-lane group ----
    #pragma unroll
    for (int off = 1; off < 16; off <<= 1)
        #pragma unroll
        for (int r = 0; r < 4; ++r)
            lp[r] += __shfl_xor(lp[r], off);

    float inv[4];
    #pragma unroll
    for (int r = 0; r < 4; ++r) inv[r] = 1.0f / lp[r];
    #pragma unroll
    for (int r = 0; r < 4; ++r) {
        short* orow = AObf + ((size_t)(bb * Tc + tq0 + quad * 4 + r)) * Ec
                           + h * HDc + l16;
        #pragma unroll
        for (int nc = 0; nc < 8; ++nc)
            orow[nc * 16] = f2bf(o[nc][r] * inv[r]);
    }
}

// ---------------------------------------------------------------------------
// Launch
// ---------------------------------------------------------------------------
extern "C" void kernel_launch(void* const* d_in, const int* in_sizes, int n_in,
                              void* d_out, int out_size, void* d_ws, size_t ws_size,
                              hipStream_t stream)
{
    const float* x    = (const float*)d_in[0];
    const int*  amask = (const int*)  d_in[1];
    const float* Wq   = (const float*)d_in[2];
    const float* bq   = (const float*)d_in[3];
    const float* Wk   = (const float*)d_in[4];
    const float* bk   = (const float*)d_in[5];
    const float* Wv   = (const float*)d_in[6];
    const float* bv   = (const float*)d_in[7];
    const float* Wo   = (const float*)d_in[8];
    const float* bo   = (const float*)d_in[9];
    float* out = (float*)d_out;

    // Workspace layout (bytes), 160 MiB + 2 MiB bitmask:
    //  [0,   64M)  Q2d fp32
    //  [64M, 96M)  Xhi bf16            -> AObf bf16 (after V-GEMM)
    //  [96M,128M)  Xlo bf16            -> V2d fp32 [96M,112M) + Khi/Klo [112M,128M)
    //  [128M,144M) WqT hi+lo           -> WkT hi/lo + WvT + WoT (after Q-GEMM)
    //  [144M,160M) K2d fp32            -> Vt bf16 (after rope_k)
    //  [160M,162M) Mbits u64
    char* ws = (char*)d_ws;
    float* Q2d   = (float*)(ws);
    short* Xhi   = (short*)(ws + 67108864);
    short* Xlo   = (short*)(ws + 100663296);
    short* WqThi = (short*)(ws + 134217728);
    short* WqTlo = (short*)(ws + 134217728 + 8388608);
    float* K2d   = (float*)(ws + 150994944);
    // overlays:
    float* V2d   = (float*)(ws + 100663296);              // over Xlo[0:16M)
    short* Khi   = (short*)(ws + 100663296 + 16777216);   // over Xlo[16M:24M)
    short* Klo   = (short*)(ws + 100663296 + 25165824);   // over Xlo[24M:32M)
    short* WkThi = (short*)(ws + 134217728);              // over WqT after Q-GEMM
    short* WkTlo = (short*)(ws + 134217728 + 2097152);
    short* WvThi = (short*)(ws + 134217728 + 4194304);
    short* WoThi = (short*)(ws + 134217728 + 8388608);
    short* Vt    = (short*)(ws + 150994944);              // over K2d after rope_k
    short* AObf  = (short*)(ws + 67108864);               // over Xhi after V-GEMM
    unsigned long long* Mb = (unsigned long long*)(ws + 167772160);

    const int M = Bc * Tc;      // 8192
    dim3 blk(256);

    // 0) mask -> bitmask (B*T*T/64 = 262144 words, 4 words/block)
    mask_bits<<<(Bc * Tc * (Tc / 64)) / 4, blk, 0, stream>>>(amask, Mb);
    // 1) Wq^T split, x split
    transpose_split<<<dim3(Ec / 32, Ec / 32), blk, 0, stream>>>(Wq, WqThi, WqTlo, Ec, Ec);
    convert_split<<<(M * Ec / 4) / 256, blk, 0, stream>>>(x, Xhi, Xlo);
    // 2) Q projection (split, fp32-fidelity)
    gemm_mfma<true><<<dim3(M / 128, Ec / 128), blk, 0, stream>>>(
        Xhi, Xlo, WqThi, WqTlo, bq, Q2d, M, Ec, Ec);
    // 3) remaining weight transposes (into the now-dead WqT slab)
    transpose_split<<<dim3(Ec / 32, KVEc / 32), blk, 0, stream>>>(Wk, WkThi, WkTlo, Ec, KVEc);
    transpose_split<<<dim3(Ec / 32, KVEc / 32), blk, 0, stream>>>(Wv, WvThi, nullptr, Ec, KVEc);
    transpose_split<<<dim3(Ec / 32, Ec / 32), blk, 0, stream>>>(Wo, WoThi, nullptr, Ec, Ec);
    // 4) K projection (split), V projection (plain)
    gemm_mfma<true><<<dim3(M / 128, KVEc / 128), blk, 0, stream>>>(
        Xhi, Xlo, WkThi, WkTlo, bk, K2d, M, KVEc, Ec);
    gemm_mfma<false><<<dim3(M / 128, KVEc / 128), blk, 0, stream>>>(
        Xhi, nullptr, WvThi, nullptr, bv, V2d, M, KVEc, Ec);
    // 5) RoPE: K -> hi/lo bf16, V -> transposed bf16
    rope_k<<<(Bc * NKVc * Tc * 64) / 256, blk, 0, stream>>>(K2d, Khi, Klo);
    rope_v_t<<<dim3(Tc / 32, NKVc, Bc), blk, 0, stream>>>(V2d, Vt);
    // 6) attention (256 threads, 64 q-rows/block) -> bf16 AO
    attn_mfma<<<dim3(Tc / 64, NHc, Bc), blk, 0, stream>>>(
        Q2d, Khi, Klo, Vt, Mb, AObf);
    // 7) output projection (plain)
    gemm_mfma<false><<<dim3(M / 128, Ec / 128), blk, 0, stream>>>(
        AObf, nullptr, WoThi, nullptr, bo, out, M, Ec, Ec);
}